// Round 8
// baseline (221.152 us; speedup 1.0000x reference)
//
#include <hip/hip_runtime.h>
#include <hip/hip_bf16.h>
#include <math.h>

// Problem constants
#define B_ 2
#define S_ 2048
#define D_ 1024
#define H_ 16
#define HD_ 64
#define BHS (B_*H_*S_)          // 65536 rows of [HD]
#define NROWS (B_*S_)           // 4096 token rows

typedef __attribute__((ext_vector_type(8))) short bf16x8;
typedef __attribute__((ext_vector_type(4))) short bf16x4;
typedef __attribute__((ext_vector_type(4))) float f32x4;

// 16x16x16 bf16 MFMA. Gate on __HIP_DEVICE_COMPILE__ (host pass can't see
// amdgcn builtins via __has_builtin).
#ifdef __HIP_DEVICE_COMPILE__
#if __has_builtin(__builtin_amdgcn_mfma_f32_16x16x16bf16_1k)
#define MFMA16(a, b, c) __builtin_amdgcn_mfma_f32_16x16x16bf16_1k(a, b, c, 0, 0, 0)
#else
#define MFMA16(a, b, c) __builtin_amdgcn_mfma_f32_16x16x16_bf16(a, b, c, 0, 0, 0)
#endif
#else
#define MFMA16(a, b, c) (c)
#endif

__device__ __forceinline__ short f2bf(float x) {
  __hip_bfloat16 h = __float2bfloat16(x);
  return *reinterpret_cast<short*>(&h);
}
// pack two floats to a packed bf16 pair, round-half-away (sign-safe): 3 VALU
__device__ __forceinline__ int packbf_hu(float lo, float hi) {
  unsigned lb = __float_as_uint(lo) + 0x8000u;
  unsigned hb = __float_as_uint(hi) + 0x8000u;
  return (int)__builtin_amdgcn_perm(hb, lb, 0x07060302u);
}

// async 16B global -> LDS (hardware adds lane*16 to the wave-uniform base)
__device__ __forceinline__ void gload_lds16(const short* g, short* l) {
  __builtin_amdgcn_global_load_lds(
      (const __attribute__((address_space(1))) void*)g,
      (__attribute__((address_space(3))) void*)l, 16, 0, 0);
}

// ---------------------------------------------------------------------------
// prep: fused fp32->bf16 casts (tokens, qkv_w, out_w) + RoPE sin/cos table.
// ---------------------------------------------------------------------------
__global__ __launch_bounds__(256) void prep(
    const float* __restrict__ tokens, const float* __restrict__ qkv_w,
    const float* __restrict__ out_w, short* __restrict__ tok_bf,
    short* __restrict__ qkvw_bf, short* __restrict__ outw_bf,
    float* __restrict__ tab) {
  const int i = blockIdx.x * 256 + threadIdx.x;
  const float* src;
  short* dst;
  int j;
  if (i < 524288) {
    src = tokens; dst = tok_bf; j = i;
  } else if (i < 917504) {
    src = qkv_w; dst = qkvw_bf; j = i - 524288;
  } else if (i < 1048576) {
    src = out_w; dst = outw_bf; j = i - 917504;
  } else if (i < 1056768) {
    const int e = (i - 1048576) * 8;     // entry = s*32 + f
    const int s = e >> 5;
    const int f0 = e & 31;
#pragma unroll
    for (int k = 0; k < 8; k++) {
      const int f = f0 + k;
      const float theta = (float)s * exp2f(-(float)f * 0.41524101186092034f);
      float sn, cs;
      sincosf(theta, &sn, &cs);
      tab[(s * 32 + f) * 2] = sn;
      tab[(s * 32 + f) * 2 + 1] = cs;
    }
    return;
  } else {
    return;
  }
  const float4 a = *(const float4*)(src + (long)j * 8);
  const float4 b = *(const float4*)(src + (long)j * 8 + 4);
  short tmp[8] = {f2bf(a.x), f2bf(a.y), f2bf(a.z), f2bf(a.w),
                  f2bf(b.x), f2bf(b.y), f2bf(b.z), f2bf(b.w)};
  *(bf16x8*)(dst + (long)j * 8) = *(const bf16x8*)tmp;
}

// ---------------------------------------------------------------------------
// qkv projection: bf16 MFMA GEMM 128x128, BK=32, 4 waves.
// Epilogues:
//  q/k: dump C-tile fp32 to per-wave LDS half-tiles (32x68), re-read row-major
//       (lane owns 4 consecutive dims -> RoPE pairs lane-internal), table
//       float4 loads, 4-shfl norm reduce, packed b64 coalesced stores.
//  v:   direct blocked-vt stores (the 16B-chunk order attn's LDS staging
//       wants): chunk c=(ntk*4+dt)*32+quad*8+e holds V[key ntk*16+quad*4+j]
//       [d=dt*16+2e+p] at pos p*4+j. C-layout keys (mt=ntk, quad, r=j) make
//       this 16 coalesced b64 stores per thread, no LDS.
// ---------------------------------------------------------------------------
__global__ __launch_bounds__(256) void qkv_mfma(
    const short* __restrict__ A, const short* __restrict__ W,
    const float* __restrict__ bias, const float* __restrict__ tab,
    short* __restrict__ qb, short* __restrict__ kb, short* __restrict__ vtb) {
  __shared__ short smem[17408];   // As|Bs (16KB); epilogue: 4 x 8704B fp32 T
  short* As = smem;
  short* Bs = smem + 4096;
  const int t = threadIdx.x;
  const int w = t >> 6;
  const int lane = t & 63;
  const int col = lane & 15;
  const int quad = lane >> 4;
  const int wm = w >> 1;
  const int wn = w & 1;
  const int m0 = blockIdx.y * 128;
  const int n0 = blockIdx.x * 128;

  f32x4 acc[4][4] = {};

  for (int k0 = 0; k0 < 1024; k0 += 32) {
    __syncthreads();
#pragma unroll
    for (int i = 0; i < 2; i++) {
      const int c = w * 2 + i;
      const int sl = c * 64 + lane;
      const int row = sl >> 2;
      const int gseg = (sl & 3) ^ (row & 3);
      gload_lds16(&A[(m0 + row) * 1024 + k0 + gseg * 8], As + c * 512);
      gload_lds16(&W[(n0 + row) * 1024 + k0 + gseg * 8], Bs + c * 512);
    }
    __syncthreads();

    bf16x8 af[4], bfr[4];
#pragma unroll
    for (int mt = 0; mt < 4; mt++) {
      const int m = wm * 64 + mt * 16 + col;
      af[mt] = *(const bf16x8*)&As[m * 32 + ((quad ^ (m & 3)) * 8)];
    }
#pragma unroll
    for (int nt = 0; nt < 4; nt++) {
      const int n = wn * 64 + nt * 16 + col;
      bfr[nt] = *(const bf16x8*)&Bs[n * 32 + ((quad ^ (n & 3)) * 8)];
    }
#pragma unroll
    for (int mt = 0; mt < 4; mt++)
#pragma unroll
      for (int nt = 0; nt < 4; nt++)
        acc[mt][nt] = __builtin_amdgcn_mfma_f32_16x16x32_bf16(
            af[mt], bfr[nt], acc[mt][nt], 0, 0, 0);
  }

  const int j_base = n0 + wn * 64;    // 64-aligned -> single (c,h), uniform/block
  const int c = j_base >> 10;
  const int h = (j_base >> 6) & 15;
  float bi[4];
#pragma unroll
  for (int nt = 0; nt < 4; nt++) bi[nt] = bias[j_base + nt * 16 + col];

  __syncthreads();   // all waves done reading As/Bs; overlay becomes valid

  if (c < 2) {
    // ---- q/k: LDS half-tile transpose + fused RoPE + L2 norm ----
    short* dst = (c == 0) ? qb : kb;
    float* Tf = (float*)smem + w * 2176;           // 32 x 68 fp32, per wave
#pragma unroll
    for (int half = 0; half < 2; half++) {
#pragma unroll
      for (int mth = 0; mth < 2; mth++) {
        const int mt = half * 2 + mth;
#pragma unroll
        for (int nt = 0; nt < 4; nt++)
#pragma unroll
          for (int r = 0; r < 4; r++)
            Tf[(mth * 16 + quad * 4 + r) * 68 + nt * 16 + col] =
                acc[mt][nt][r] + bi[nt];
      }
      // wave-private round trip; compiler inserts lgkmcnt waits
#pragma unroll
      for (int p = 0; p < 8; p++) {
        const int rloc = p * 4 + quad;
        const int n = m0 + wm * 64 + half * 32 + rloc;
        const int bidx = n >> 11;
        const int s = n & 2047;
        const float4 xv = *(const float4*)&Tf[rloc * 68 + col * 4];
        const float4 tc = *(const float4*)&tab[s * 64 + col * 4];
        const float e0 = xv.x * tc.y - xv.y * tc.x;
        const float o0 = xv.x * tc.x + xv.y * tc.y;
        const float e1 = xv.z * tc.w - xv.w * tc.z;
        const float o1 = xv.z * tc.z + xv.w * tc.w;
        float ss = e0 * e0 + o0 * o0 + e1 * e1 + o1 * o1;
        ss += __shfl_xor(ss, 1, 64);
        ss += __shfl_xor(ss, 2, 64);
        ss += __shfl_xor(ss, 4, 64);
        ss += __shfl_xor(ss, 8, 64);
        const float scl = 1.0f / fmaxf(sqrtf(ss), 1e-12f);
        int2 pk;
        pk.x = packbf_hu(e0 * scl, o0 * scl);
        pk.y = packbf_hu(e1 * scl, o1 * scl);
        *(int2*)&dst[((long)(bidx * 16 + h) * 2048 + s) * 64 + col * 4] = pk;
      }
    }
  } else {
    // ---- v: direct blocked-vt coalesced stores ----
    const int n64 = m0 + wm * 64;
    const int bidx = n64 >> 11;
    const int st = (n64 & 2047) >> 6;
    short* vbase = vtb + ((long)(bidx * 16 + h) * 32 + st) * 4096;
#pragma unroll
    for (int mt = 0; mt < 4; mt++)
#pragma unroll
      for (int ntq = 0; ntq < 4; ntq++) {
        int2 pk;
        pk.x = packbf_hu(acc[mt][ntq][0] + bi[ntq], acc[mt][ntq][1] + bi[ntq]);
        pk.y = packbf_hu(acc[mt][ntq][2] + bi[ntq], acc[mt][ntq][3] + bi[ntq]);
        *(int2*)&vbase[((mt * 4 + ntq) * 32 + quad * 8 + (col >> 1)) * 8 +
                       (col & 1) * 4] = pk;
      }
  }
}

// ---------------------------------------------------------------------------
// MFMA streaming attention, S^T formulation, in-register P.
// Block = 256 threads = 2 key-groups x 2 waves; q-tile 64/block (each wave
// 32 q-rows); grid (32 bh, 32 q-tiles) = 1024 blocks = 4/CU.
// K LDS chunks: c = nt*128 + h*64 + quad*16 + col (16B global-contiguous,
// reads = base + lane*16B, conflict-free). V comes pre-blocked from qkv
// (global chunk index == LDS chunk index): staging is sequential chunks,
// b64 fragment reads = base + lane*8B, conflict-free.
// O written directly from registers (no LDS bounce); the two key-groups'
// partial (sum e*v, sum e) combine through an LDS overlay (valid since
// |score| <= 1/8 -> no max subtraction).
// ---------------------------------------------------------------------------
__global__ __launch_bounds__(256) void attn_mfma(
    const short* __restrict__ qb,  // [B,H,S,64]
    const short* __restrict__ kb,  // [B,H,S,64]
    const short* __restrict__ vt,  // [B,H,32 tiles,4096] blocked
    short* __restrict__ ob) {      // [B,H,S,64]
  __shared__ __align__(16) char smem[32768];  // Kf[2][4096]s | Vf[2][4096]s
  short* Kf = (short*)smem;                   // overlay: Ocomb[64][68]f+lsumC
  short* Vf = Kf + 8192;
  const int t = threadIdx.x;
  const int w = t >> 6;            // 0..3
  const int grp = w >> 1;          // key-split group
  const int wl = w & 1;            // wave within group
  const int lane = t & 63;
  const int col = lane & 15;
  const int quad = lane >> 4;
  const int bh = blockIdx.x;
  const int q0 = blockIdx.y * 64;
  const long hb = (long)bh * S_ * 64;
  const short* kg = kb + hb;
  const short* vg = vt + (long)bh * 64 * S_;

  // Q B-fragments (16x16x32): rows q0+wl*32+mt2*16+col, dims h*32+quad*8+j
  bf16x8 qa[2][2];
#pragma unroll
  for (int mt2 = 0; mt2 < 2; mt2++)
#pragma unroll
    for (int h = 0; h < 2; h++)
      qa[mt2][h] = *(const bf16x8*)&qb[hb +
          (long)(q0 + wl * 32 + mt2 * 16 + col) * 64 + h * 32 + quad * 8];

  // staging: per group 128 threads stage 512 K-chunks + 512 V-chunks (4+4 ea)
  const int tt = (wl << 6) | lane;   // 0..127 within group
  int kofs[4];
#pragma unroll
  for (int i = 0; i < 4; i++) {
    const int cc = tt + 128 * i;
    kofs[i] = ((cc >> 7) * 16 + (cc & 15)) * 64 + ((cc >> 6) & 1) * 32 +
              ((cc >> 4) & 3) * 8;
  }

  short* KfL = Kf + grp * 4096;
  short* VfL = Vf + grp * 4096;

  f32x4 oacc[2][4] = {};
  float lsum[2] = {0.f, 0.f};

  const int kend = grp * 1024 + 1024;
  for (int kt = grp * 1024; kt < kend; kt += 64) {
    __syncthreads();
    const short* kgp = kg + (long)kt * 64;
    const short* vgp = vg + (kt >> 6) * 4096;
#pragma unroll
    for (int i = 0; i < 4; i++)
      gload_lds16(kgp + kofs[i], KfL + wl * 512 + i * 1024);
#pragma unroll
    for (int i = 0; i < 4; i++)
      gload_lds16(vgp + tt * 8 + i * 1024, VfL + wl * 512 + i * 1024);
    __syncthreads();

#pragma unroll
    for (int nt = 0; nt < 4; nt++) {
      const bf16x8 ka0 = *(const bf16x8*)&KfL[nt * 1024 + quad * 128 + col * 8];
      const bf16x8 ka1 =
          *(const bf16x8*)&KfL[nt * 1024 + 512 + quad * 128 + col * 8];
      bf16x4 pb[2];
#pragma unroll
      for (int mt2 = 0; mt2 < 2; mt2++) {
        f32x4 z = {0.f, 0.f, 0.f, 0.f};
        z = __builtin_amdgcn_mfma_f32_16x16x32_bf16(ka0, qa[mt2][0], z, 0, 0, 0);
        z = __builtin_amdgcn_mfma_f32_16x16x32_bf16(ka1, qa[mt2][1], z, 0, 0, 0);
        const float e0 = __expf(z[0] * 0.125f);
        const float e1 = __expf(z[1] * 0.125f);
        const float e2 = __expf(z[2] * 0.125f);
        const float e3 = __expf(z[3] * 0.125f);
        lsum[mt2] += (e0 + e1) + (e2 + e3);
        int pk[2] = {packbf_hu(e0, e1), packbf_hu(e2, e3)};
        pb[mt2] = *(const bf16x4*)pk;
      }
#pragma unroll
      for (int dt = 0; dt < 4; dt++) {
        const bf16x4 va =
            *(const bf16x4*)&VfL[(nt * 4 + dt) * 256 + quad * 64 + col * 4];
        oacc[0][dt] = MFMA16(va, pb[0], oacc[0][dt]);
        oacc[1][dt] = MFMA16(va, pb[1], oacc[1][dt]);
      }
    }
  }

  __syncthreads();   // staging dead; overlay becomes valid

  // reduce lsum over quads (lanes sharing col hold same-q partials)
#pragma unroll
  for (int mt2 = 0; mt2 < 2; mt2++) {
    float s = lsum[mt2];
    s += __shfl_xor(s, 16, 64);
    s += __shfl_xor(s, 32, 64);
    lsum[mt2] = s;
  }

  float* Ocomb = (float*)smem;                 // [64][68]
  float* lsumC = (float*)(smem + 17408);       // [64]
  if (grp == 1) {
#pragma unroll
    for (int mt2 = 0; mt2 < 2; mt2++) {
      const int qloc = wl * 32 + mt2 * 16 + col;
      if (quad == 0) lsumC[qloc] = lsum[mt2];
#pragma unroll
      for (int dt = 0; dt < 4; dt++)
        *(f32x4*)&Ocomb[qloc * 68 + dt * 16 + quad * 4] = oacc[mt2][dt];
    }
  }
  __syncthreads();
  if (grp == 0) {
#pragma unroll
    for (int mt2 = 0; mt2 < 2; mt2++) {
      const int qloc = wl * 32 + mt2 * 16 + col;
      const float inv = 1.0f / (lsum[mt2] + lsumC[qloc]);
      short* orow = ob + hb + (long)(q0 + qloc) * 64;
#pragma unroll
      for (int dt = 0; dt < 4; dt++) {
        const float4 oc = *(const float4*)&Ocomb[qloc * 68 + dt * 16 + quad * 4];
        int2 pk;
        pk.x = packbf_hu((oacc[mt2][dt][0] + oc.x) * inv,
                         (oacc[mt2][dt][1] + oc.y) * inv);
        pk.y = packbf_hu((oacc[mt2][dt][2] + oc.z) * inv,
                         (oacc[mt2][dt][3] + oc.w) * inv);
        *(int2*)&orow[dt * 16 + quad * 4] = pk;
      }
    }
  }
}

// ---------------------------------------------------------------------------
// out projection: 64x128 tile (grid 512 = 2 blocks/CU), BK=32, 4 waves (2x2).
// A = O bf16 [B,H,S,64] (k -> (h,hd) remap in staging), fp32 out + bias.
// ---------------------------------------------------------------------------
__global__ __launch_bounds__(256) void out_mfma(
    const short* __restrict__ O, const short* __restrict__ W,
    const float* __restrict__ bias, float* __restrict__ out) {
  __shared__ short As[64 * 32];    // 256 x 16B chunks
  __shared__ short Bs[128 * 32];   // 512 chunks
  const int t = threadIdx.x;
  const int w = t >> 6;
  const int lane = t & 63;
  const int col = lane & 15;
  const int quad = lane >> 4;
  const int wm = w >> 1;
  const int wn = w & 1;
  const int m0 = blockIdx.y * 64;
  const int n0 = blockIdx.x * 128;

  f32x4 acc[2][4] = {};

  for (int k0 = 0; k0 < 1024; k0 += 32) {
    __syncthreads();
    {
      const int row = t >> 2;
      const int gseg = (t & 3) ^ (row & 3);
      const int n = m0 + row;
      const int bidx = n >> 11;
      const int s = n & 2047;
      const int kk = k0 + gseg * 8;
      gload_lds16(&O[((long)(bidx * 16 + (kk >> 6)) * 2048 + s) * 64 + (kk & 63)],
                  As + w * 512);
    }
#pragma unroll
    for (int i = 0; i < 2; i++) {
      const int cs = w * 2 + i;
      const int sl = cs * 64 + lane;
      const int row = sl >> 2;
      const int gseg = (sl & 3) ^ (row & 3);
      gload_lds16(&W[(n0 + row) * 1024 + k0 + gseg * 8], Bs + cs * 512);
    }
    __syncthreads();

    bf16x8 af[2], bfr[4];
#pragma unroll
    for (int mt = 0; mt < 2; mt++) {
      const int m = wm * 32 + mt * 16 + col;
      af[mt] = *(const bf16x8*)&As[m * 32 + ((quad ^ (m & 3)) * 8)];
    }
#pragma unroll
    for (int nt = 0; nt < 4; nt++) {
      const int n = wn * 64 + nt * 16 + col;
      bfr[nt] = *(const bf16x8*)&Bs[n * 32 + ((quad ^ (n & 3)) * 8)];
    }
#pragma unroll
    for (int mt = 0; mt < 2; mt++)
#pragma unroll
      for (int nt = 0; nt < 4; nt++)
        acc[mt][nt] = __builtin_amdgcn_mfma_f32_16x16x32_bf16(
            af[mt], bfr[nt], acc[mt][nt], 0, 0, 0);
  }

  float bi[4];
#pragma unroll
  for (int nt = 0; nt < 4; nt++) bi[nt] = bias[n0 + wn * 64 + nt * 16 + col];
#pragma unroll
  for (int mt = 0; mt < 2; mt++) {
#pragma unroll
    for (int r = 0; r < 4; r++) {
      const int n = m0 + wm * 32 + mt * 16 + quad * 4 + r;
#pragma unroll
      for (int nt = 0; nt < 4; nt++)
        out[(long)n * 1024 + n0 + wn * 64 + nt * 16 + col] =
            acc[mt][nt][r] + bi[nt];
    }
  }
}

// ---------------------------------------------------------------------------
extern "C" void kernel_launch(void* const* d_in, const int* in_sizes, int n_in,
                              void* d_out, int out_size, void* d_ws,
                              size_t ws_size, hipStream_t stream) {
  const float* tokens = (const float*)d_in[0];
  const float* qkv_w = (const float*)d_in[1];
  const float* qkv_b = (const float*)d_in[2];
  const float* out_w = (const float*)d_in[3];
  const float* out_b = (const float*)d_in[4];
  float* out = (float*)d_out;

  const size_t per = (size_t)BHS * HD_;          // 4,194,304 elements
  float* tab = (float*)d_ws;                     // 2048*32*2 floats = 512 KB
  short* tok_bf = (short*)(tab + 2048 * 64);
  short* qkvw_bf = tok_bf + per;                 // 3M shorts
  short* outw_bf = qkvw_bf + 3 * per / 4;        // 1M
  short* q_bf = outw_bf + per / 4;               // 4M
  short* k_bf = q_bf + per;                      // 4M
  short* vt_bf = k_bf + per;                     // 4M (blocked layout)
  short* O_bf = vt_bf + per;                     // 4M  (~48.5 MB total)

  // 1) casts + rope table
  hipLaunchKernelGGL(prep, dim3(4128), dim3(256), 0, stream, tokens, qkv_w,
                     out_w, tok_bf, qkvw_bf, outw_bf, tab);
  // 2) QKV projection + fused RoPE/norm (q,k) + blocked-vt stores (v)
  hipLaunchKernelGGL(qkv_mfma, dim3(24, 32), dim3(256), 0, stream, tok_bf,
                     qkvw_bf, qkv_b, tab, q_bf, k_bf, vt_bf);
  // 3) Attention (S^T, in-register P, conflict-free staging, 4 blocks/CU)
  hipLaunchKernelGGL(attn_mfma, dim3(B_ * H_, S_ / 64), dim3(256), 0, stream,
                     q_bf, k_bf, vt_bf, O_bf);
  // 4) Output projection
  hipLaunchKernelGGL(out_mfma, dim3(8, 64), dim3(256), 0, stream, O_bf,
                     outw_bf, out_b, out);
}

// Round 9
// 208.274 us; speedup vs baseline: 1.0618x; 1.0618x over previous
//
#include <hip/hip_runtime.h>
#include <hip/hip_bf16.h>
#include <math.h>

// Problem constants
#define B_ 2
#define S_ 2048
#define D_ 1024
#define H_ 16
#define HD_ 64
#define BHS (B_*H_*S_)          // 65536 rows of [HD]
#define NROWS (B_*S_)           // 4096 token rows

typedef __attribute__((ext_vector_type(8))) short bf16x8;
typedef __attribute__((ext_vector_type(4))) short bf16x4;
typedef __attribute__((ext_vector_type(4))) float f32x4;

// Device-only builtins: gate on __HIP_DEVICE_COMPILE__ (host pass can't see
// amdgcn builtins via __has_builtin).
#ifdef __HIP_DEVICE_COMPILE__
#if __has_builtin(__builtin_amdgcn_mfma_f32_16x16x16bf16_1k)
#define MFMA16(a, b, c) __builtin_amdgcn_mfma_f32_16x16x16bf16_1k(a, b, c, 0, 0, 0)
#else
#define MFMA16(a, b, c) __builtin_amdgcn_mfma_f32_16x16x16_bf16(a, b, c, 0, 0, 0)
#endif
#define EXP2(x) __builtin_amdgcn_exp2f(x)
#else
#define MFMA16(a, b, c) (c)
#define EXP2(x) exp2f(x)
#endif

// SCALE * log2(e) = 0.125 * 1.4426950408889634
#define SCALE_LOG2E 0.18033688011112043f

__device__ __forceinline__ short f2bf(float x) {
  __hip_bfloat16 h = __float2bfloat16(x);
  return *reinterpret_cast<short*>(&h);
}
// pack two floats to a packed bf16 pair, round-half-away: 3 VALU ops
__device__ __forceinline__ int packbf_hu(float lo, float hi) {
  unsigned lb = __float_as_uint(lo) + 0x8000u;
  unsigned hb = __float_as_uint(hi) + 0x8000u;
  return (int)__builtin_amdgcn_perm(hb, lb, 0x07060302u);
}

// async 16B global -> LDS (hardware adds lane*16 to the wave-uniform base)
__device__ __forceinline__ void gload_lds16(const short* g, short* l) {
  __builtin_amdgcn_global_load_lds(
      (const __attribute__((address_space(1))) void*)g,
      (__attribute__((address_space(3))) void*)l, 16, 0, 0);
}

// ---------------------------------------------------------------------------
// prep: fused fp32->bf16 casts (tokens, qkv_w, out_w) + RoPE sin/cos table.
// ---------------------------------------------------------------------------
__global__ __launch_bounds__(256) void prep(
    const float* __restrict__ tokens, const float* __restrict__ qkv_w,
    const float* __restrict__ out_w, short* __restrict__ tok_bf,
    short* __restrict__ qkvw_bf, short* __restrict__ outw_bf,
    float* __restrict__ tab) {
  const int i = blockIdx.x * 256 + threadIdx.x;
  const float* src;
  short* dst;
  int j;
  if (i < 524288) {
    src = tokens; dst = tok_bf; j = i;
  } else if (i < 917504) {
    src = qkv_w; dst = qkvw_bf; j = i - 524288;
  } else if (i < 1048576) {
    src = out_w; dst = outw_bf; j = i - 917504;
  } else if (i < 1056768) {
    const int e = (i - 1048576) * 8;     // entry = s*32 + f
    const int s = e >> 5;
    const int f0 = e & 31;
#pragma unroll
    for (int k = 0; k < 8; k++) {
      const int f = f0 + k;
      const float theta = (float)s * exp2f(-(float)f * 0.41524101186092034f);
      float sn, cs;
      sincosf(theta, &sn, &cs);
      tab[(s * 32 + f) * 2] = sn;
      tab[(s * 32 + f) * 2 + 1] = cs;
    }
    return;
  } else {
    return;
  }
  const float4 a = *(const float4*)(src + (long)j * 8);
  const float4 b = *(const float4*)(src + (long)j * 8 + 4);
  short tmp[8] = {f2bf(a.x), f2bf(a.y), f2bf(a.z), f2bf(a.w),
                  f2bf(b.x), f2bf(b.y), f2bf(b.z), f2bf(b.w)};
  *(bf16x8*)(dst + (long)j * 8) = *(const bf16x8*)tmp;
}

// ---------------------------------------------------------------------------
// qkv projection: bf16 MFMA GEMM 128x128, BK=32, 4 waves.
// Epilogues: q/k LDS half-tile transpose + fused RoPE/L2-norm; v direct
// blocked-vt coalesced stores (the 16B-chunk order attn's staging wants).
// ---------------------------------------------------------------------------
__global__ __launch_bounds__(256) void qkv_mfma(
    const short* __restrict__ A, const short* __restrict__ W,
    const float* __restrict__ bias, const float* __restrict__ tab,
    short* __restrict__ qb, short* __restrict__ kb, short* __restrict__ vtb) {
  __shared__ short smem[17408];   // As|Bs (16KB); epilogue: 4 x 8704B fp32 T
  short* As = smem;
  short* Bs = smem + 4096;
  const int t = threadIdx.x;
  const int w = t >> 6;
  const int lane = t & 63;
  const int col = lane & 15;
  const int quad = lane >> 4;
  const int wm = w >> 1;
  const int wn = w & 1;
  const int m0 = blockIdx.y * 128;
  const int n0 = blockIdx.x * 128;

  f32x4 acc[4][4] = {};

  for (int k0 = 0; k0 < 1024; k0 += 32) {
    __syncthreads();
#pragma unroll
    for (int i = 0; i < 2; i++) {
      const int c = w * 2 + i;
      const int sl = c * 64 + lane;
      const int row = sl >> 2;
      const int gseg = (sl & 3) ^ (row & 3);
      gload_lds16(&A[(m0 + row) * 1024 + k0 + gseg * 8], As + c * 512);
      gload_lds16(&W[(n0 + row) * 1024 + k0 + gseg * 8], Bs + c * 512);
    }
    __syncthreads();

    bf16x8 af[4], bfr[4];
#pragma unroll
    for (int mt = 0; mt < 4; mt++) {
      const int m = wm * 64 + mt * 16 + col;
      af[mt] = *(const bf16x8*)&As[m * 32 + ((quad ^ (m & 3)) * 8)];
    }
#pragma unroll
    for (int nt = 0; nt < 4; nt++) {
      const int n = wn * 64 + nt * 16 + col;
      bfr[nt] = *(const bf16x8*)&Bs[n * 32 + ((quad ^ (n & 3)) * 8)];
    }
#pragma unroll
    for (int mt = 0; mt < 4; mt++)
#pragma unroll
      for (int nt = 0; nt < 4; nt++)
        acc[mt][nt] = __builtin_amdgcn_mfma_f32_16x16x32_bf16(
            af[mt], bfr[nt], acc[mt][nt], 0, 0, 0);
  }

  const int j_base = n0 + wn * 64;    // 64-aligned -> single (c,h), uniform/block
  const int c = j_base >> 10;
  const int h = (j_base >> 6) & 15;
  float bi[4];
#pragma unroll
  for (int nt = 0; nt < 4; nt++) bi[nt] = bias[j_base + nt * 16 + col];

  __syncthreads();   // all waves done reading As/Bs; overlay becomes valid

  if (c < 2) {
    // ---- q/k: LDS half-tile transpose + fused RoPE + L2 norm ----
    short* dst = (c == 0) ? qb : kb;
    float* Tf = (float*)smem + w * 2176;           // 32 x 68 fp32, per wave
#pragma unroll
    for (int half = 0; half < 2; half++) {
#pragma unroll
      for (int mth = 0; mth < 2; mth++) {
        const int mt = half * 2 + mth;
#pragma unroll
        for (int nt = 0; nt < 4; nt++)
#pragma unroll
          for (int r = 0; r < 4; r++)
            Tf[(mth * 16 + quad * 4 + r) * 68 + nt * 16 + col] =
                acc[mt][nt][r] + bi[nt];
      }
      // wave-private round trip; compiler inserts lgkmcnt waits
#pragma unroll
      for (int p = 0; p < 8; p++) {
        const int rloc = p * 4 + quad;
        const int n = m0 + wm * 64 + half * 32 + rloc;
        const int bidx = n >> 11;
        const int s = n & 2047;
        const float4 xv = *(const float4*)&Tf[rloc * 68 + col * 4];
        const float4 tc = *(const float4*)&tab[s * 64 + col * 4];
        const float e0 = xv.x * tc.y - xv.y * tc.x;
        const float o0 = xv.x * tc.x + xv.y * tc.y;
        const float e1 = xv.z * tc.w - xv.w * tc.z;
        const float o1 = xv.z * tc.z + xv.w * tc.w;
        float ss = e0 * e0 + o0 * o0 + e1 * e1 + o1 * o1;
        ss += __shfl_xor(ss, 1, 64);
        ss += __shfl_xor(ss, 2, 64);
        ss += __shfl_xor(ss, 4, 64);
        ss += __shfl_xor(ss, 8, 64);
        const float scl = 1.0f / fmaxf(sqrtf(ss), 1e-12f);
        int2 pk;
        pk.x = packbf_hu(e0 * scl, o0 * scl);
        pk.y = packbf_hu(e1 * scl, o1 * scl);
        *(int2*)&dst[((long)(bidx * 16 + h) * 2048 + s) * 64 + col * 4] = pk;
      }
    }
  } else {
    // ---- v: direct blocked-vt coalesced stores ----
    const int n64 = m0 + wm * 64;
    const int bidx = n64 >> 11;
    const int st = (n64 & 2047) >> 6;
    short* vbase = vtb + ((long)(bidx * 16 + h) * 32 + st) * 4096;
#pragma unroll
    for (int mt = 0; mt < 4; mt++)
#pragma unroll
      for (int ntq = 0; ntq < 4; ntq++) {
        int2 pk;
        pk.x = packbf_hu(acc[mt][ntq][0] + bi[ntq], acc[mt][ntq][1] + bi[ntq]);
        pk.y = packbf_hu(acc[mt][ntq][2] + bi[ntq], acc[mt][ntq][3] + bi[ntq]);
        *(int2*)&vbase[((mt * 4 + ntq) * 32 + quad * 8 + (col >> 1)) * 8 +
                       (col & 1) * 4] = pk;
      }
  }
}

// ---------------------------------------------------------------------------
// MFMA streaming attention: round-7 shape (512 thr, 2 key-groups x 4 waves,
// q-tile 128) + round-8 conflict-free layouts + MFMA-computed denominator.
// S^T = mfma32(K-frag, Q-frag); P stays in registers (C-layout == B-operand
// of mfma16); PV and row-sum (ones-MFMA) on the matrix pipe. exp via raw
// v_exp_f32 with folded SCALE*log2e. Partials of the two key-groups combine
// through an LDS overlay (no max subtraction needed: |score| <= 1/8).
// ---------------------------------------------------------------------------
__global__ __launch_bounds__(512) void attn_mfma(
    const short* __restrict__ qb,  // [B,H,S,64]
    const short* __restrict__ kb,  // [B,H,S,64]
    const short* __restrict__ vt,  // [B,H,32 tiles,4096] blocked
    short* __restrict__ ob) {      // [B,H,S,64]
  // staging: Kf[2][4096]s (16KB) + Vf[2][4096]s (16KB)
  // overlay after loop: Ocomb fp32[128][68] (34816B) + lsumC[128] (512B)
  __shared__ __align__(16) char smem[35328];
  short* Kf = (short*)smem;
  short* Vf = Kf + 8192;
  const int t = threadIdx.x;
  const int w = t >> 6;            // 0..7
  const int grp = w >> 2;          // key-split group
  const int wl = w & 3;            // wave within group
  const int lane = t & 63;
  const int col = lane & 15;
  const int quad = lane >> 4;
  const int bh = blockIdx.x;
  const int q0 = blockIdx.y * 128;
  const long hb = (long)bh * S_ * 64;
  const short* kg = kb + hb;
  const short* vg = vt + (long)bh * 64 * S_;

  // Q B-fragments (16x16x32): rows q0+wl*32+mt2*16+col, dims h*32+quad*8+j
  bf16x8 qa[2][2];
#pragma unroll
  for (int mt2 = 0; mt2 < 2; mt2++)
#pragma unroll
    for (int h = 0; h < 2; h++)
      qa[mt2][h] = *(const bf16x8*)&qb[hb +
          (long)(q0 + wl * 32 + mt2 * 16 + col) * 64 + h * 32 + quad * 8];

  // staging: per group 256 threads stage 512 K-chunks + 512 V-chunks (2 ea)
  const int tt = (wl << 6) | lane;   // 0..255 within group
  int kofs[2];
#pragma unroll
  for (int i = 0; i < 2; i++) {
    const int cc = tt + 256 * i;
    kofs[i] = ((cc >> 7) * 16 + (cc & 15)) * 64 + ((cc >> 6) & 1) * 32 +
              ((cc >> 4) & 3) * 8;
  }

  short* KfL = Kf + grp * 4096;
  short* VfL = Vf + grp * 4096;

  f32x4 oacc[2][4] = {};
  f32x4 lacc[2] = {};
  const short oneb = 0x3F80;   // bf16 1.0
  const bf16x4 ones = {oneb, oneb, oneb, oneb};

  const int kend = grp * 1024 + 1024;
  for (int kt = grp * 1024; kt < kend; kt += 64) {
    __syncthreads();
    const short* kgp = kg + (long)kt * 64;
    const short* vgp = vg + (long)(kt >> 6) * 4096;
#pragma unroll
    for (int i = 0; i < 2; i++) {
      gload_lds16(kgp + kofs[i], KfL + i * 2048 + wl * 512);
      gload_lds16(vgp + (tt + 256 * i) * 8, VfL + i * 2048 + wl * 512);
    }
    __syncthreads();

#pragma unroll
    for (int nt = 0; nt < 4; nt++) {
      const bf16x8 ka0 = *(const bf16x8*)&KfL[nt * 1024 + quad * 128 + col * 8];
      const bf16x8 ka1 =
          *(const bf16x8*)&KfL[nt * 1024 + 512 + quad * 128 + col * 8];
      bf16x4 pb[2];
#pragma unroll
      for (int mt2 = 0; mt2 < 2; mt2++) {
        f32x4 z = {0.f, 0.f, 0.f, 0.f};
        z = __builtin_amdgcn_mfma_f32_16x16x32_bf16(ka0, qa[mt2][0], z, 0, 0, 0);
        z = __builtin_amdgcn_mfma_f32_16x16x32_bf16(ka1, qa[mt2][1], z, 0, 0, 0);
        const float e0 = EXP2(z[0] * SCALE_LOG2E);
        const float e1 = EXP2(z[1] * SCALE_LOG2E);
        const float e2 = EXP2(z[2] * SCALE_LOG2E);
        const float e3 = EXP2(z[3] * SCALE_LOG2E);
        int pk[2] = {packbf_hu(e0, e1), packbf_hu(e2, e3)};
        pb[mt2] = *(const bf16x4*)pk;
        lacc[mt2] = MFMA16(ones, pb[mt2], lacc[mt2]);  // row-sum on matrix pipe
      }
#pragma unroll
      for (int dt = 0; dt < 4; dt++) {
        const bf16x4 va =
            *(const bf16x4*)&VfL[(nt * 4 + dt) * 256 + quad * 64 + col * 4];
        oacc[0][dt] = MFMA16(va, pb[0], oacc[0][dt]);
        oacc[1][dt] = MFMA16(va, pb[1], oacc[1][dt]);
      }
    }
  }

  __syncthreads();   // staging dead; overlay becomes valid
  // lacc[mt2][r] (any r) = this group's sum of exp for q=col (all rows equal)

  float* Ocomb = (float*)smem;                 // [128][68]
  float* lsumC = (float*)(smem + 34816);       // [128]
  if (grp == 1) {
#pragma unroll
    for (int mt2 = 0; mt2 < 2; mt2++) {
      const int qloc = wl * 32 + mt2 * 16 + col;
      if (quad == 0) lsumC[qloc] = lacc[mt2][0];
#pragma unroll
      for (int dt = 0; dt < 4; dt++)
        *(f32x4*)&Ocomb[qloc * 68 + dt * 16 + quad * 4] = oacc[mt2][dt];
    }
  }
  __syncthreads();
  if (grp == 0) {
#pragma unroll
    for (int mt2 = 0; mt2 < 2; mt2++) {
      const int qloc = wl * 32 + mt2 * 16 + col;
      const float inv = 1.0f / (lacc[mt2][0] + lsumC[qloc]);
      short* orow = ob + hb + (long)(q0 + qloc) * 64;
#pragma unroll
      for (int dt = 0; dt < 4; dt++) {
        const float4 oc = *(const float4*)&Ocomb[qloc * 68 + dt * 16 + quad * 4];
        int2 pk;
        pk.x = packbf_hu((oacc[mt2][dt][0] + oc.x) * inv,
                         (oacc[mt2][dt][1] + oc.y) * inv);
        pk.y = packbf_hu((oacc[mt2][dt][2] + oc.z) * inv,
                         (oacc[mt2][dt][3] + oc.w) * inv);
        *(int2*)&orow[dt * 16 + quad * 4] = pk;
      }
    }
  }
}

// ---------------------------------------------------------------------------
// out projection: 64x128 tile (grid 512 = 2 blocks/CU), BK=32, 4 waves (2x2).
// A = O bf16 [B,H,S,64] (k -> (h,hd) remap in staging), fp32 out + bias.
// ---------------------------------------------------------------------------
__global__ __launch_bounds__(256) void out_mfma(
    const short* __restrict__ O, const short* __restrict__ W,
    const float* __restrict__ bias, float* __restrict__ out) {
  __shared__ short As[64 * 32];    // 256 x 16B chunks
  __shared__ short Bs[128 * 32];   // 512 chunks
  const int t = threadIdx.x;
  const int w = t >> 6;
  const int lane = t & 63;
  const int col = lane & 15;
  const int quad = lane >> 4;
  const int wm = w >> 1;
  const int wn = w & 1;
  const int m0 = blockIdx.y * 64;
  const int n0 = blockIdx.x * 128;

  f32x4 acc[2][4] = {};

  for (int k0 = 0; k0 < 1024; k0 += 32) {
    __syncthreads();
    {
      const int row = t >> 2;
      const int gseg = (t & 3) ^ (row & 3);
      const int n = m0 + row;
      const int bidx = n >> 11;
      const int s = n & 2047;
      const int kk = k0 + gseg * 8;
      gload_lds16(&O[((long)(bidx * 16 + (kk >> 6)) * 2048 + s) * 64 + (kk & 63)],
                  As + w * 512);
    }
#pragma unroll
    for (int i = 0; i < 2; i++) {
      const int cs = w * 2 + i;
      const int sl = cs * 64 + lane;
      const int row = sl >> 2;
      const int gseg = (sl & 3) ^ (row & 3);
      gload_lds16(&W[(n0 + row) * 1024 + k0 + gseg * 8], Bs + cs * 512);
    }
    __syncthreads();

    bf16x8 af[2], bfr[4];
#pragma unroll
    for (int mt = 0; mt < 2; mt++) {
      const int m = wm * 32 + mt * 16 + col;
      af[mt] = *(const bf16x8*)&As[m * 32 + ((quad ^ (m & 3)) * 8)];
    }
#pragma unroll
    for (int nt = 0; nt < 4; nt++) {
      const int n = wn * 64 + nt * 16 + col;
      bfr[nt] = *(const bf16x8*)&Bs[n * 32 + ((quad ^ (n & 3)) * 8)];
    }
#pragma unroll
    for (int mt = 0; mt < 2; mt++)
#pragma unroll
      for (int nt = 0; nt < 4; nt++)
        acc[mt][nt] = __builtin_amdgcn_mfma_f32_16x16x32_bf16(
            af[mt], bfr[nt], acc[mt][nt], 0, 0, 0);
  }

  float bi[4];
#pragma unroll
  for (int nt = 0; nt < 4; nt++) bi[nt] = bias[n0 + wn * 64 + nt * 16 + col];
#pragma unroll
  for (int mt = 0; mt < 2; mt++) {
#pragma unroll
    for (int r = 0; r < 4; r++) {
      const int n = m0 + wm * 32 + mt * 16 + quad * 4 + r;
#pragma unroll
      for (int nt = 0; nt < 4; nt++)
        out[(long)n * 1024 + n0 + wn * 64 + nt * 16 + col] =
            acc[mt][nt][r] + bi[nt];
    }
  }
}

// ---------------------------------------------------------------------------
extern "C" void kernel_launch(void* const* d_in, const int* in_sizes, int n_in,
                              void* d_out, int out_size, void* d_ws,
                              size_t ws_size, hipStream_t stream) {
  const float* tokens = (const float*)d_in[0];
  const float* qkv_w = (const float*)d_in[1];
  const float* qkv_b = (const float*)d_in[2];
  const float* out_w = (const float*)d_in[3];
  const float* out_b = (const float*)d_in[4];
  float* out = (float*)d_out;

  const size_t per = (size_t)BHS * HD_;          // 4,194,304 elements
  float* tab = (float*)d_ws;                     // 2048*32*2 floats = 512 KB
  short* tok_bf = (short*)(tab + 2048 * 64);
  short* qkvw_bf = tok_bf + per;                 // 3M shorts
  short* outw_bf = qkvw_bf + 3 * per / 4;        // 1M
  short* q_bf = outw_bf + per / 4;               // 4M
  short* k_bf = q_bf + per;                      // 4M
  short* vt_bf = k_bf + per;                     // 4M (blocked layout)
  short* O_bf = vt_bf + per;                     // 4M  (~48.5 MB total)

  // 1) casts + rope table
  hipLaunchKernelGGL(prep, dim3(4128), dim3(256), 0, stream, tokens, qkv_w,
                     out_w, tok_bf, qkvw_bf, outw_bf, tab);
  // 2) QKV projection + fused RoPE/norm (q,k) + blocked-vt stores (v)
  hipLaunchKernelGGL(qkv_mfma, dim3(24, 32), dim3(256), 0, stream, tok_bf,
                     qkvw_bf, qkv_b, tab, q_bf, k_bf, vt_bf);
  // 3) Attention (512 thr, q-tile 128, conflict-free staging, MFMA denom)
  hipLaunchKernelGGL(attn_mfma, dim3(B_ * H_, S_ / 128), dim3(512), 0, stream,
                     q_bf, k_bf, vt_bf, O_bf);
  // 4) Output projection
  hipLaunchKernelGGL(out_mfma, dim3(8, 64), dim3(256), 0, stream, O_bf,
                     outw_bf, out_b, out);
}

// Round 10
// 201.939 us; speedup vs baseline: 1.0951x; 1.0314x over previous
//
#include <hip/hip_runtime.h>
#include <hip/hip_bf16.h>
#include <math.h>

// Problem constants
#define B_ 2
#define S_ 2048
#define D_ 1024
#define H_ 16
#define HD_ 64
#define BHS (B_*H_*S_)          // 65536 rows of [HD]
#define NROWS (B_*S_)           // 4096 token rows

typedef __attribute__((ext_vector_type(8))) short bf16x8;
typedef __attribute__((ext_vector_type(4))) short bf16x4;
typedef __attribute__((ext_vector_type(4))) float f32x4;

// Device-only builtins: gate on __HIP_DEVICE_COMPILE__ (host pass can't see
// amdgcn builtins via __has_builtin).
#ifdef __HIP_DEVICE_COMPILE__
#if __has_builtin(__builtin_amdgcn_mfma_f32_16x16x16bf16_1k)
#define MFMA16(a, b, c) __builtin_amdgcn_mfma_f32_16x16x16bf16_1k(a, b, c, 0, 0, 0)
#else
#define MFMA16(a, b, c) __builtin_amdgcn_mfma_f32_16x16x16_bf16(a, b, c, 0, 0, 0)
#endif
#define EXP2(x) __builtin_amdgcn_exp2f(x)
#else
#define MFMA16(a, b, c) (c)
#define EXP2(x) exp2f(x)
#endif

// SCALE * log2(e) = 0.125 * 1.4426950408889634
#define SCALE_LOG2E 0.18033688011112043f

__device__ __forceinline__ short f2bf(float x) {
  __hip_bfloat16 h = __float2bfloat16(x);
  return *reinterpret_cast<short*>(&h);
}
// pack two floats to a packed bf16 pair, round-half-away: 3 VALU ops
__device__ __forceinline__ int packbf_hu(float lo, float hi) {
  unsigned lb = __float_as_uint(lo) + 0x8000u;
  unsigned hb = __float_as_uint(hi) + 0x8000u;
  return (int)__builtin_amdgcn_perm(hb, lb, 0x07060302u);
}

// async 16B global -> LDS (hardware adds lane*16 to the wave-uniform base)
__device__ __forceinline__ void gload_lds16(const short* g, short* l) {
  __builtin_amdgcn_global_load_lds(
      (const __attribute__((address_space(1))) void*)g,
      (__attribute__((address_space(3))) void*)l, 16, 0, 0);
}

// ---------------------------------------------------------------------------
// prep: fused fp32->bf16 casts (tokens, qkv_w, out_w) + RoPE sin/cos table.
// ---------------------------------------------------------------------------
__global__ __launch_bounds__(256) void prep(
    const float* __restrict__ tokens, const float* __restrict__ qkv_w,
    const float* __restrict__ out_w, short* __restrict__ tok_bf,
    short* __restrict__ qkvw_bf, short* __restrict__ outw_bf,
    float* __restrict__ tab) {
  const int i = blockIdx.x * 256 + threadIdx.x;
  const float* src;
  short* dst;
  int j;
  if (i < 524288) {
    src = tokens; dst = tok_bf; j = i;
  } else if (i < 917504) {
    src = qkv_w; dst = qkvw_bf; j = i - 524288;
  } else if (i < 1048576) {
    src = out_w; dst = outw_bf; j = i - 917504;
  } else if (i < 1056768) {
    const int e = (i - 1048576) * 8;     // entry = s*32 + f
    const int s = e >> 5;
    const int f0 = e & 31;
#pragma unroll
    for (int k = 0; k < 8; k++) {
      const int f = f0 + k;
      const float theta = (float)s * exp2f(-(float)f * 0.41524101186092034f);
      float sn, cs;
      sincosf(theta, &sn, &cs);
      tab[(s * 32 + f) * 2] = sn;
      tab[(s * 32 + f) * 2 + 1] = cs;
    }
    return;
  } else {
    return;
  }
  const float4 a = *(const float4*)(src + (long)j * 8);
  const float4 b = *(const float4*)(src + (long)j * 8 + 4);
  short tmp[8] = {f2bf(a.x), f2bf(a.y), f2bf(a.z), f2bf(a.w),
                  f2bf(b.x), f2bf(b.y), f2bf(b.z), f2bf(b.w)};
  *(bf16x8*)(dst + (long)j * 8) = *(const bf16x8*)tmp;
}

// ---------------------------------------------------------------------------
// qkv projection: bf16 MFMA GEMM, 64x128 tile (m x n), BK=32, 4 waves (2x2,
// wave piece 32x64). Grid 1536 linear = 6 blocks/CU (vs 3 at 128-tile) —
// attacks the round-9 latency stall (Occupancy 14.7%, MfmaUtil 16.5%).
// XCD swizzle: 24 n-tiles / 8 XCDs = 3 per XCD -> W-slice 768 KB L2-resident.
// Epilogues: q/k LDS 16-row transpose + fused RoPE/L2-norm; v direct
// blocked-vt coalesced stores.
// ---------------------------------------------------------------------------
__global__ __launch_bounds__(256) void qkv_mfma(
    const short* __restrict__ A, const short* __restrict__ W,
    const float* __restrict__ bias, const float* __restrict__ tab,
    short* __restrict__ qb, short* __restrict__ kb, short* __restrict__ vtb) {
  __shared__ short smem[8704];    // staging As[2048]|Bs[4096]; epi: 4x16x68 f32
  short* As = smem;
  short* Bs = smem + 2048;
  const int t = threadIdx.x;
  const int w = t >> 6;
  const int lane = t & 63;
  const int col = lane & 15;
  const int quad = lane >> 4;
  const int wm = w >> 1;
  const int wn = w & 1;
  const int bid = blockIdx.x;     // 0..1535
  const int xcd = bid & 7;
  const int seq = bid >> 3;       // 0..191
  const int m0 = (seq / 3) * 64;
  const int n0 = (xcd * 3 + seq % 3) * 128;

  f32x4 acc[2][4] = {};

  for (int k0 = 0; k0 < 1024; k0 += 32) {
    __syncthreads();
    {  // A: 256 chunks, 1 per thread; wave-uniform LDS base + lane*16
      const int c = w * 64 + lane;
      const int row = c >> 2;
      const int gseg = (c & 3) ^ (row & 3);
      gload_lds16(&A[(m0 + row) * 1024 + k0 + gseg * 8], As + w * 512);
    }
#pragma unroll
    for (int i = 0; i < 2; i++) {  // B: 512 chunks, 2 per thread
      const int c0 = i * 256 + w * 64;
      const int c = c0 + lane;
      const int row = c >> 2;
      const int gseg = (c & 3) ^ (row & 3);
      gload_lds16(&W[(n0 + row) * 1024 + k0 + gseg * 8], Bs + c0 * 8);
    }
    __syncthreads();

    bf16x8 af[2], bfr[4];
#pragma unroll
    for (int mt = 0; mt < 2; mt++) {
      const int m = wm * 32 + mt * 16 + col;
      af[mt] = *(const bf16x8*)&As[m * 32 + ((quad ^ (m & 3)) * 8)];
    }
#pragma unroll
    for (int nt = 0; nt < 4; nt++) {
      const int n = wn * 64 + nt * 16 + col;
      bfr[nt] = *(const bf16x8*)&Bs[n * 32 + ((quad ^ (n & 3)) * 8)];
    }
#pragma unroll
    for (int mt = 0; mt < 2; mt++)
#pragma unroll
      for (int nt = 0; nt < 4; nt++)
        acc[mt][nt] = __builtin_amdgcn_mfma_f32_16x16x32_bf16(
            af[mt], bfr[nt], acc[mt][nt], 0, 0, 0);
  }

  const int j_base = n0 + wn * 64;    // 64-aligned -> single (c,h), uniform/wave
  const int c = j_base >> 10;
  const int h = (j_base >> 6) & 15;
  float bi[4];
#pragma unroll
  for (int nt = 0; nt < 4; nt++) bi[nt] = bias[j_base + nt * 16 + col];

  __syncthreads();   // all waves done reading As/Bs; overlay becomes valid

  if (c < 2) {
    // ---- q/k: per-wave 16-row LDS transpose + fused RoPE + L2 norm ----
    short* dst = (c == 0) ? qb : kb;
    float* Tf = (float*)smem + w * 1088;           // 16 x 68 fp32, per wave
#pragma unroll
    for (int mt = 0; mt < 2; mt++) {
#pragma unroll
      for (int nt = 0; nt < 4; nt++)
#pragma unroll
        for (int r = 0; r < 4; r++)
          Tf[(quad * 4 + r) * 68 + nt * 16 + col] = acc[mt][nt][r] + bi[nt];
      // wave-private round trip (same-wave LDS ops are ordered)
#pragma unroll
      for (int p = 0; p < 4; p++) {
        const int rloc = p * 4 + quad;
        const int n = m0 + wm * 32 + mt * 16 + rloc;
        const int bidx = n >> 11;
        const int s = n & 2047;
        const float4 xv = *(const float4*)&Tf[rloc * 68 + col * 4];
        const float4 tc = *(const float4*)&tab[s * 64 + col * 4];
        const float e0 = xv.x * tc.y - xv.y * tc.x;
        const float o0 = xv.x * tc.x + xv.y * tc.y;
        const float e1 = xv.z * tc.w - xv.w * tc.z;
        const float o1 = xv.z * tc.z + xv.w * tc.w;
        float ss = e0 * e0 + o0 * o0 + e1 * e1 + o1 * o1;
        ss += __shfl_xor(ss, 1, 64);
        ss += __shfl_xor(ss, 2, 64);
        ss += __shfl_xor(ss, 4, 64);
        ss += __shfl_xor(ss, 8, 64);
        const float scl = 1.0f / fmaxf(sqrtf(ss), 1e-12f);
        int2 pk;
        pk.x = packbf_hu(e0 * scl, o0 * scl);
        pk.y = packbf_hu(e1 * scl, o1 * scl);
        *(int2*)&dst[((long)(bidx * 16 + h) * 2048 + s) * 64 + col * 4] = pk;
      }
      // next mt reuses Tf: same-wave in-order LDS ops, no barrier needed
    }
  } else {
    // ---- v: direct blocked-vt coalesced stores (m-tile = exactly 1 ktile) ----
    const int bidx = m0 >> 11;
    const int st = (m0 & 2047) >> 6;
    short* vbase = vtb + ((long)(bidx * 16 + h) * 32 + st) * 4096;
#pragma unroll
    for (int mt = 0; mt < 2; mt++)
#pragma unroll
      for (int ntq = 0; ntq < 4; ntq++) {
        int2 pk;
        pk.x = packbf_hu(acc[mt][ntq][0] + bi[ntq], acc[mt][ntq][1] + bi[ntq]);
        pk.y = packbf_hu(acc[mt][ntq][2] + bi[ntq], acc[mt][ntq][3] + bi[ntq]);
        *(int2*)&vbase[(((wm * 2 + mt) * 4 + ntq) * 32 + quad * 8 +
                        (col >> 1)) * 8 + (col & 1) * 4] = pk;
      }
  }
}

// ---------------------------------------------------------------------------
// MFMA streaming attention (unchanged from round 9): 512 thr, 2 key-groups x
// 4 waves, q-tile 128, conflict-free staging, in-register P, MFMA denominator.
// ---------------------------------------------------------------------------
__global__ __launch_bounds__(512) void attn_mfma(
    const short* __restrict__ qb,  // [B,H,S,64]
    const short* __restrict__ kb,  // [B,H,S,64]
    const short* __restrict__ vt,  // [B,H,32 tiles,4096] blocked
    short* __restrict__ ob) {      // [B,H,S,64]
  __shared__ __align__(16) char smem[35328];
  short* Kf = (short*)smem;
  short* Vf = Kf + 8192;
  const int t = threadIdx.x;
  const int w = t >> 6;            // 0..7
  const int grp = w >> 2;          // key-split group
  const int wl = w & 3;            // wave within group
  const int lane = t & 63;
  const int col = lane & 15;
  const int quad = lane >> 4;
  const int bh = blockIdx.x;
  const int q0 = blockIdx.y * 128;
  const long hb = (long)bh * S_ * 64;
  const short* kg = kb + hb;
  const short* vg = vt + (long)bh * 64 * S_;

  bf16x8 qa[2][2];
#pragma unroll
  for (int mt2 = 0; mt2 < 2; mt2++)
#pragma unroll
    for (int h = 0; h < 2; h++)
      qa[mt2][h] = *(const bf16x8*)&qb[hb +
          (long)(q0 + wl * 32 + mt2 * 16 + col) * 64 + h * 32 + quad * 8];

  const int tt = (wl << 6) | lane;   // 0..255 within group
  int kofs[2];
#pragma unroll
  for (int i = 0; i < 2; i++) {
    const int cc = tt + 256 * i;
    kofs[i] = ((cc >> 7) * 16 + (cc & 15)) * 64 + ((cc >> 6) & 1) * 32 +
              ((cc >> 4) & 3) * 8;
  }

  short* KfL = Kf + grp * 4096;
  short* VfL = Vf + grp * 4096;

  f32x4 oacc[2][4] = {};
  f32x4 lacc[2] = {};
  const short oneb = 0x3F80;   // bf16 1.0
  const bf16x4 ones = {oneb, oneb, oneb, oneb};

  const int kend = grp * 1024 + 1024;
  for (int kt = grp * 1024; kt < kend; kt += 64) {
    __syncthreads();
    const short* kgp = kg + (long)kt * 64;
    const short* vgp = vg + (long)(kt >> 6) * 4096;
#pragma unroll
    for (int i = 0; i < 2; i++) {
      gload_lds16(kgp + kofs[i], KfL + i * 2048 + wl * 512);
      gload_lds16(vgp + (tt + 256 * i) * 8, VfL + i * 2048 + wl * 512);
    }
    __syncthreads();

#pragma unroll
    for (int nt = 0; nt < 4; nt++) {
      const bf16x8 ka0 = *(const bf16x8*)&KfL[nt * 1024 + quad * 128 + col * 8];
      const bf16x8 ka1 =
          *(const bf16x8*)&KfL[nt * 1024 + 512 + quad * 128 + col * 8];
      bf16x4 pb[2];
#pragma unroll
      for (int mt2 = 0; mt2 < 2; mt2++) {
        f32x4 z = {0.f, 0.f, 0.f, 0.f};
        z = __builtin_amdgcn_mfma_f32_16x16x32_bf16(ka0, qa[mt2][0], z, 0, 0, 0);
        z = __builtin_amdgcn_mfma_f32_16x16x32_bf16(ka1, qa[mt2][1], z, 0, 0, 0);
        const float e0 = EXP2(z[0] * SCALE_LOG2E);
        const float e1 = EXP2(z[1] * SCALE_LOG2E);
        const float e2 = EXP2(z[2] * SCALE_LOG2E);
        const float e3 = EXP2(z[3] * SCALE_LOG2E);
        int pk[2] = {packbf_hu(e0, e1), packbf_hu(e2, e3)};
        pb[mt2] = *(const bf16x4*)pk;
        lacc[mt2] = MFMA16(ones, pb[mt2], lacc[mt2]);  // row-sum on matrix pipe
      }
#pragma unroll
      for (int dt = 0; dt < 4; dt++) {
        const bf16x4 va =
            *(const bf16x4*)&VfL[(nt * 4 + dt) * 256 + quad * 64 + col * 4];
        oacc[0][dt] = MFMA16(va, pb[0], oacc[0][dt]);
        oacc[1][dt] = MFMA16(va, pb[1], oacc[1][dt]);
      }
    }
  }

  __syncthreads();   // staging dead; overlay becomes valid

  float* Ocomb = (float*)smem;                 // [128][68]
  float* lsumC = (float*)(smem + 34816);       // [128]
  if (grp == 1) {
#pragma unroll
    for (int mt2 = 0; mt2 < 2; mt2++) {
      const int qloc = wl * 32 + mt2 * 16 + col;
      if (quad == 0) lsumC[qloc] = lacc[mt2][0];
#pragma unroll
      for (int dt = 0; dt < 4; dt++)
        *(f32x4*)&Ocomb[qloc * 68 + dt * 16 + quad * 4] = oacc[mt2][dt];
    }
  }
  __syncthreads();
  if (grp == 0) {
#pragma unroll
    for (int mt2 = 0; mt2 < 2; mt2++) {
      const int qloc = wl * 32 + mt2 * 16 + col;
      const float inv = 1.0f / (lacc[mt2][0] + lsumC[qloc]);
      short* orow = ob + hb + (long)(q0 + qloc) * 64;
#pragma unroll
      for (int dt = 0; dt < 4; dt++) {
        const float4 oc = *(const float4*)&Ocomb[qloc * 68 + dt * 16 + quad * 4];
        int2 pk;
        pk.x = packbf_hu((oacc[mt2][dt][0] + oc.x) * inv,
                         (oacc[mt2][dt][1] + oc.y) * inv);
        pk.y = packbf_hu((oacc[mt2][dt][2] + oc.z) * inv,
                         (oacc[mt2][dt][3] + oc.w) * inv);
        *(int2*)&orow[dt * 16 + quad * 4] = pk;
      }
    }
  }
}

// ---------------------------------------------------------------------------
// out projection: 64x64 tile, grid 1024 = 4 blocks/CU (was 2), BK=32,
// 4 waves (2x2, wave piece 32x32). XCD swizzle: 16 n-tiles / 8 XCDs = 2 each.
// A = O bf16 [B,H,S,64] (k -> (h,hd) remap in staging), fp32 out + bias.
// ---------------------------------------------------------------------------
__global__ __launch_bounds__(256) void out_mfma(
    const short* __restrict__ O, const short* __restrict__ W,
    const float* __restrict__ bias, float* __restrict__ out) {
  __shared__ short As[2048];    // 64x32
  __shared__ short Bs[2048];    // 64x32
  const int t = threadIdx.x;
  const int w = t >> 6;
  const int lane = t & 63;
  const int col = lane & 15;
  const int quad = lane >> 4;
  const int wm = w >> 1;
  const int wn = w & 1;
  const int bid = blockIdx.x;     // 0..1023
  const int xcd = bid & 7;
  const int seq = bid >> 3;       // 0..127
  const int m0 = (seq >> 1) * 64;
  const int n0 = (xcd * 2 + (seq & 1)) * 64;

  f32x4 acc[2][2] = {};

  for (int k0 = 0; k0 < 1024; k0 += 32) {
    __syncthreads();
    {
      const int c = w * 64 + lane;
      const int row = c >> 2;
      const int gseg = (c & 3) ^ (row & 3);
      const int n = m0 + row;
      const int bidx = n >> 11;
      const int s = n & 2047;
      const int kk = k0 + gseg * 8;
      gload_lds16(&O[((long)(bidx * 16 + (kk >> 6)) * 2048 + s) * 64 + (kk & 63)],
                  As + w * 512);
    }
    {
      const int c = w * 64 + lane;
      const int row = c >> 2;
      const int gseg = (c & 3) ^ (row & 3);
      gload_lds16(&W[(n0 + row) * 1024 + k0 + gseg * 8], Bs + w * 512);
    }
    __syncthreads();

    bf16x8 af[2], bfr[2];
#pragma unroll
    for (int mt = 0; mt < 2; mt++) {
      const int m = wm * 32 + mt * 16 + col;
      af[mt] = *(const bf16x8*)&As[m * 32 + ((quad ^ (m & 3)) * 8)];
    }
#pragma unroll
    for (int nt = 0; nt < 2; nt++) {
      const int n = wn * 32 + nt * 16 + col;
      bfr[nt] = *(const bf16x8*)&Bs[n * 32 + ((quad ^ (n & 3)) * 8)];
    }
#pragma unroll
    for (int mt = 0; mt < 2; mt++)
#pragma unroll
      for (int nt = 0; nt < 2; nt++)
        acc[mt][nt] = __builtin_amdgcn_mfma_f32_16x16x32_bf16(
            af[mt], bfr[nt], acc[mt][nt], 0, 0, 0);
  }

  float bi[2];
#pragma unroll
  for (int nt = 0; nt < 2; nt++) bi[nt] = bias[n0 + wn * 32 + nt * 16 + col];
#pragma unroll
  for (int mt = 0; mt < 2; mt++) {
#pragma unroll
    for (int r = 0; r < 4; r++) {
      const int n = m0 + wm * 32 + mt * 16 + quad * 4 + r;
#pragma unroll
      for (int nt = 0; nt < 2; nt++)
        out[(long)n * 1024 + n0 + wn * 32 + nt * 16 + col] =
            acc[mt][nt][r] + bi[nt];
    }
  }
}

// ---------------------------------------------------------------------------
extern "C" void kernel_launch(void* const* d_in, const int* in_sizes, int n_in,
                              void* d_out, int out_size, void* d_ws,
                              size_t ws_size, hipStream_t stream) {
  const float* tokens = (const float*)d_in[0];
  const float* qkv_w = (const float*)d_in[1];
  const float* qkv_b = (const float*)d_in[2];
  const float* out_w = (const float*)d_in[3];
  const float* out_b = (const float*)d_in[4];
  float* out = (float*)d_out;

  const size_t per = (size_t)BHS * HD_;          // 4,194,304 elements
  float* tab = (float*)d_ws;                     // 2048*32*2 floats = 512 KB
  short* tok_bf = (short*)(tab + 2048 * 64);
  short* qkvw_bf = tok_bf + per;                 // 3M shorts
  short* outw_bf = qkvw_bf + 3 * per / 4;        // 1M
  short* q_bf = outw_bf + per / 4;               // 4M
  short* k_bf = q_bf + per;                      // 4M
  short* vt_bf = k_bf + per;                     // 4M (blocked layout)
  short* O_bf = vt_bf + per;                     // 4M  (~48.5 MB total)

  // 1) casts + rope table
  hipLaunchKernelGGL(prep, dim3(4128), dim3(256), 0, stream, tokens, qkv_w,
                     out_w, tok_bf, qkvw_bf, outw_bf, tab);
  // 2) QKV projection (64x128 tiles, 6 blocks/CU, XCD swizzle) + fused
  //    RoPE/norm + blocked-vt stores
  hipLaunchKernelGGL(qkv_mfma, dim3(1536), dim3(256), 0, stream, tok_bf,
                     qkvw_bf, qkv_b, tab, q_bf, k_bf, vt_bf);
  // 3) Attention (unchanged)
  hipLaunchKernelGGL(attn_mfma, dim3(B_ * H_, S_ / 128), dim3(512), 0, stream,
                     q_bf, k_bf, vt_bf, O_bf);
  // 4) Output projection (64x64 tiles, 4 blocks/CU, XCD swizzle)
  hipLaunchKernelGGL(out_mfma, dim3(1024), dim3(256), 0, stream, O_bf,
                     outw_bf, out_b, out);
}